// Round 1
// baseline (58547.345 us; speedup 1.0000x reference)
//
#include <hip/hip_runtime.h>
#include <stdint.h>

// ---------------------------------------------------------------------------
// StabilizedNeuralODE v2: zero inter-workgroup communication.
//
// Previous design (48.5 ms) split weights across 8 CUs and paid 9,198
// sequential L3-coherent barrier rounds (5.3 us each; MfmaUtil 1%).
// This design: 32 independent WGs, each owns 16 batch rows for the whole
// trajectory. Weights are pre-converted once to bf16 (row-major, in d_ws)
// and STREAMED from the XCD-local L2 every stage (w1+w2+w3 = 768 KB/stage;
// all weights fit easily in a 4 MiB XCD L2, so steady-state reads are L2
// hits). A (32 KB) is cached in LDS. Activations (y/h1/h2/k) live in LDS,
// exchanged only via __syncthreads().
//
// Per stage per WG: 800 MFMAs (0.4 us/wave) hidden under the 768 KB weight
// stream (~3-5 us at 150-250 GB/s per-CU L2 BW). B-fragment loads are
// issued one k-step ahead of the MFMAs that consume them (manual depth-1
// pipeline), 8 KB/wave in flight.
//
// MFMA 16x16x32_bf16 layout (same as verified baseline):
//   A-frag: A[m=lane&15][k=quad*8+j]; B-frag: B[n=lane&15][k=quad*8+j];
//   C/D:    n=lane&15, m=quad*4+reg.
// ---------------------------------------------------------------------------

#define Dd 128
#define Ww 512
#define Tt 512
#define NSTEP 511
#define NWG 32
#define MROW 16
#define NTHR 256

// workspace layout (ushort element offsets): bf16 row-major weights
#define WS_W1 0         // 512 x 128
#define WS_W2 65536     // 512 x 512
#define WS_W3 327680    // 128 x 512
#define WS_TOT 393216   // 786,432 bytes

// LDS layout (ushort element offsets)
#define HPAD 520
#define YPAD 136
#define OFF_H1 0                    // 16 x 520
#define OFF_H2 8320                 // 16 x 520
#define OFF_Y  16640                // 16 x 136
#define OFF_A  18816                // 128 x 136
#define USH_TOT 36224
// float region (float element offsets from fr)
#define FOFF_K  0                   // 6 buffers of 16x128 (k1..k6)
#define FOFF_B1 12288               // 512
#define FOFF_B2 12800               // 512
#define FOFF_B3 13312               // 128
#define FTOT    13440
#define SMEM_BYTES (USH_TOT * 2 + FTOT * 4)   // 72448 + 53760 = 126208

typedef __attribute__((ext_vector_type(8))) __bf16 bf16x8;
typedef __attribute__((ext_vector_type(4))) float f32x4;

__device__ __forceinline__ unsigned short f2b(float f) {
  union { float f; unsigned int u; } v; v.f = f;
  return (unsigned short)((v.u + 0x7fffu + ((v.u >> 16) & 1u)) >> 16);
}
__device__ __forceinline__ void st4bf(unsigned short* dst, float4 v) {
  union { unsigned short u[4]; uint2 q; } p;
  p.u[0] = f2b(v.x); p.u[1] = f2b(v.y); p.u[2] = f2b(v.z); p.u[3] = f2b(v.w);
  *(uint2*)dst = p.q;
}
__device__ __forceinline__ float fast_tanh(float x) {
  x = fminf(fmaxf(x, -15.f), 15.f);
  float e = __expf(2.f * x);
  return (e - 1.f) / (e + 1.f);
}

// RK tables in device-global const memory (dynamically indexed by stage s ->
// must NOT be a per-thread local array, which would go to scratch).
__device__ const float ATABg[5][5] = {
  {0.161f, 0.f, 0.f, 0.f, 0.f},
  {-0.008480655492356989f, 0.335480655492357f, 0.f, 0.f, 0.f},
  {2.8971530571054935f, -6.359448489975075f, 4.3622954328695815f, 0.f, 0.f},
  {5.325864828439257f, -11.748883564062828f, 7.4955393428898365f,
   -0.09249506636175525f, 0.f},
  {5.86145544294642f, -12.92096931784711f, 8.159367898576159f,
   -0.071584973281401f, -0.028269050394068383f}};
__device__ const float BTABg[6] = {
  0.09646076681806523f, 0.01f, 0.4798896504144996f, 1.379008574103742f,
  -3.290069515436081f, 2.324710524099774f};

// one-time fp32 -> bf16 weight pack into workspace (row-major)
__global__ void prep_kernel(const float* __restrict__ w1,
                            const float* __restrict__ w2,
                            const float* __restrict__ w3,
                            unsigned short* __restrict__ wsb) {
  for (int i = blockIdx.x * blockDim.x + threadIdx.x; i < WS_TOT;
       i += gridDim.x * blockDim.x) {
    float v;
    if (i < WS_W2)      v = w1[i];
    else if (i < WS_W3) v = w2[i - WS_W2];
    else                v = w3[i - WS_W3];
    wsb[i] = f2b(v);
  }
}

__global__ void __launch_bounds__(NTHR, 1)
ode_kernel(const float* __restrict__ ts,
           const float* __restrict__ yi,
           const float* __restrict__ b1,
           const float* __restrict__ b2,
           const float* __restrict__ b3,
           const float* __restrict__ Am,
           float* __restrict__ out,
           const unsigned short* __restrict__ wsb)
{
  extern __shared__ unsigned short smem[];
  unsigned short* h1s = smem + OFF_H1;
  unsigned short* h2s = smem + OFF_H2;
  unsigned short* ysl = smem + OFF_Y;
  unsigned short* Asl = smem + OFF_A;
  float* fr  = (float*)(smem + USH_TOT);
  float* b1s = fr + FOFF_B1;
  float* b2s = fr + FOFF_B2;
  float* b3s = fr + FOFF_B3;

  const int tid  = threadIdx.x;
  const int wid  = tid >> 6;
  const int lane = tid & 63;
  const int l16  = lane & 15;
  const int quad = lane >> 4;
  const int koq  = quad * 8;
  const int b0   = blockIdx.x * MROW;

  const unsigned short* w1b = wsb + WS_W1;
  const unsigned short* w2b = wsb + WS_W2;
  const unsigned short* w3b = wsb + WS_W3;

  // ---- one-time staging: biases (fp32) + A (bf16) into LDS ----
  for (int i = tid; i < Ww; i += NTHR) { b1s[i] = b1[i]; b2s[i] = b2[i]; }
  if (tid < Dd) b3s[tid] = b3[tid];
  for (int i = tid; i < Dd * 32; i += NTHR) {       // A: 128 x 128
    int r = i >> 5, c = (i & 31) * 4;
    st4bf(Asl + r * YPAD + c, *(const float4*)(Am + r * Dd + c));
  }

  // ---- y0: fp32 regs (8/thread), ysl bf16, out[t=0] fp32 ----
  const int yr = tid >> 4;
  const int yc = (tid & 15) * 8;
  float y[8];
  {
    float4 v0 = *(const float4*)(yi + (b0 + yr) * Dd + yc);
    float4 v1 = *(const float4*)(yi + (b0 + yr) * Dd + yc + 4);
    y[0] = v0.x; y[1] = v0.y; y[2] = v0.z; y[3] = v0.w;
    y[4] = v1.x; y[5] = v1.y; y[6] = v1.z; y[7] = v1.w;
    st4bf(ysl + yr * YPAD + yc, v0);
    st4bf(ysl + yr * YPAD + yc + 4, v1);
    float* op = out + (size_t)(b0 + yr) * (Tt * Dd) + yc;
    *(float4*)op = v0;
    *(float4*)(op + 4) = v1;
  }
  __syncthreads();

  const int nbA = wid * 128;   // phase A/B: wave's 128-wide hidden chunk
  const int nbC = wid * 32;    // phase C:   wave's 32-wide output chunk

  for (int t = 0; t < NSTEP; ++t) {
    float hdt = ts[t + 1] - ts[t];

    for (int s = 0; s < 6; ++s) {
      float* kb = fr + FOFF_K + (s << 11);   // this stage's k buffer (16x128)

      // -------- phase A: h1 = tanh(a @ w1.T + b1), stream w1 --------------
      {
        f32x4 acc[8];
        #pragma unroll
        for (int nt = 0; nt < 8; ++nt) { f32x4 z = {0.f,0.f,0.f,0.f}; acc[nt] = z; }
        const unsigned short* bp = w1b + (nbA + l16) * Dd + koq;
        const unsigned short* ap = ysl + l16 * YPAD + koq;
        bf16x8 bb[8];
        #pragma unroll
        for (int nt = 0; nt < 8; ++nt)
          bb[nt] = *(const bf16x8*)(bp + nt * 16 * Dd);
        #pragma unroll
        for (int ks = 0; ks < 4; ++ks) {
          bf16x8 bn[8];
          if (ks < 3) {
            #pragma unroll
            for (int nt = 0; nt < 8; ++nt)
              bn[nt] = *(const bf16x8*)(bp + nt * 16 * Dd + (ks + 1) * 32);
          }
          bf16x8 af = *(const bf16x8*)(ap + ks * 32);
          #pragma unroll
          for (int nt = 0; nt < 8; ++nt)
            acc[nt] = __builtin_amdgcn_mfma_f32_16x16x32_bf16(af, bb[nt],
                                                              acc[nt], 0, 0, 0);
          if (ks < 3) {
            #pragma unroll
            for (int nt = 0; nt < 8; ++nt) bb[nt] = bn[nt];
          }
        }
        #pragma unroll
        for (int nt = 0; nt < 8; ++nt) {
          int n = nbA + nt * 16 + l16;
          float bias = b1s[n];
          #pragma unroll
          for (int r = 0; r < 4; ++r)
            h1s[(quad * 4 + r) * HPAD + n] = f2b(fast_tanh(acc[nt][r] + bias));
        }
      }
      __syncthreads();

      // -------- phase B: h2 = tanh(h1 @ w2.T + b2), stream w2 -------------
      {
        f32x4 acc[8];
        #pragma unroll
        for (int nt = 0; nt < 8; ++nt) { f32x4 z = {0.f,0.f,0.f,0.f}; acc[nt] = z; }
        const unsigned short* bp = w2b + (nbA + l16) * Ww + koq;
        const unsigned short* ap = h1s + l16 * HPAD + koq;
        bf16x8 bb[8];
        #pragma unroll
        for (int nt = 0; nt < 8; ++nt)
          bb[nt] = *(const bf16x8*)(bp + nt * 16 * Ww);
        #pragma unroll
        for (int ks = 0; ks < 16; ++ks) {
          bf16x8 bn[8];
          if (ks < 15) {
            #pragma unroll
            for (int nt = 0; nt < 8; ++nt)
              bn[nt] = *(const bf16x8*)(bp + nt * 16 * Ww + (ks + 1) * 32);
          }
          bf16x8 af = *(const bf16x8*)(ap + ks * 32);
          #pragma unroll
          for (int nt = 0; nt < 8; ++nt)
            acc[nt] = __builtin_amdgcn_mfma_f32_16x16x32_bf16(af, bb[nt],
                                                              acc[nt], 0, 0, 0);
          if (ks < 15) {
            #pragma unroll
            for (int nt = 0; nt < 8; ++nt) bb[nt] = bn[nt];
          }
        }
        #pragma unroll
        for (int nt = 0; nt < 8; ++nt) {
          int n = nbA + nt * 16 + l16;
          float bias = b2s[n];
          #pragma unroll
          for (int r = 0; r < 4; ++r)
            h2s[(quad * 4 + r) * HPAD + n] = f2b(fast_tanh(acc[nt][r] + bias));
        }
      }
      __syncthreads();

      // -------- phase C: k = h2 @ w3.T + b3 + a @ A.T (stream w3; A in LDS)
      {
        f32x4 acc0 = {0.f, 0.f, 0.f, 0.f};
        f32x4 acc1 = {0.f, 0.f, 0.f, 0.f};
        const unsigned short* bp = w3b + (nbC + l16) * Ww + koq;
        const unsigned short* ap = h2s + l16 * HPAD + koq;
        bf16x8 bb0 = *(const bf16x8*)(bp);
        bf16x8 bb1 = *(const bf16x8*)(bp + 16 * Ww);
        #pragma unroll
        for (int ks = 0; ks < 16; ++ks) {
          bf16x8 bn0, bn1;
          if (ks < 15) {
            bn0 = *(const bf16x8*)(bp + (ks + 1) * 32);
            bn1 = *(const bf16x8*)(bp + 16 * Ww + (ks + 1) * 32);
          }
          bf16x8 af = *(const bf16x8*)(ap + ks * 32);
          acc0 = __builtin_amdgcn_mfma_f32_16x16x32_bf16(af, bb0, acc0, 0, 0, 0);
          acc1 = __builtin_amdgcn_mfma_f32_16x16x32_bf16(af, bb1, acc1, 0, 0, 0);
          if (ks < 15) { bb0 = bn0; bb1 = bn1; }
        }
        const unsigned short* apy = ysl + l16 * YPAD + koq;
        const unsigned short* bpA = Asl + (nbC + l16) * YPAD + koq;
        #pragma unroll
        for (int ks = 0; ks < 4; ++ks) {
          bf16x8 af = *(const bf16x8*)(apy + ks * 32);
          acc0 = __builtin_amdgcn_mfma_f32_16x16x32_bf16(
              af, *(const bf16x8*)(bpA + ks * 32), acc0, 0, 0, 0);
          acc1 = __builtin_amdgcn_mfma_f32_16x16x32_bf16(
              af, *(const bf16x8*)(bpA + 16 * YPAD + ks * 32), acc1, 0, 0, 0);
        }
        {
          int n = nbC + l16;
          float bias = b3s[n];
          #pragma unroll
          for (int r = 0; r < 4; ++r)
            kb[(quad * 4 + r) * Dd + n] = acc0[r] + bias;
        }
        {
          int n = nbC + 16 + l16;
          float bias = b3s[n];
          #pragma unroll
          for (int r = 0; r < 4; ++r)
            kb[(quad * 4 + r) * Dd + n] = acc1[r] + bias;
        }
      }
      __syncthreads();

      // -------- phase D: RK combine (fp32; k's read from LDS) -------------
      {
        float a[8];
        #pragma unroll
        for (int j = 0; j < 8; ++j) a[j] = y[j];
        if (s < 5) {
          for (int q = 0; q <= s; ++q) {
            float c = hdt * ATABg[s][q];
            const float* kq = fr + FOFF_K + (q << 11) + yr * Dd + yc;
            float4 k0 = *(const float4*)kq;
            float4 k1 = *(const float4*)(kq + 4);
            a[0] += c * k0.x; a[1] += c * k0.y; a[2] += c * k0.z; a[3] += c * k0.w;
            a[4] += c * k1.x; a[5] += c * k1.y; a[6] += c * k1.z; a[7] += c * k1.w;
          }
        } else {
          for (int q = 0; q < 6; ++q) {
            float c = hdt * BTABg[q];
            const float* kq = fr + FOFF_K + (q << 11) + yr * Dd + yc;
            float4 k0 = *(const float4*)kq;
            float4 k1 = *(const float4*)(kq + 4);
            a[0] += c * k0.x; a[1] += c * k0.y; a[2] += c * k0.z; a[3] += c * k0.w;
            a[4] += c * k1.x; a[5] += c * k1.y; a[6] += c * k1.z; a[7] += c * k1.w;
          }
          #pragma unroll
          for (int j = 0; j < 8; ++j) y[j] = a[j];
        }
        float4 v0 = {a[0], a[1], a[2], a[3]};
        float4 v1 = {a[4], a[5], a[6], a[7]};
        st4bf(ysl + yr * YPAD + yc, v0);
        st4bf(ysl + yr * YPAD + yc + 4, v1);
        if (s == 5) {
          float* op = out + (size_t)(b0 + yr) * (Tt * Dd) +
                      (size_t)(t + 1) * Dd + yc;
          *(float4*)op = v0;
          *(float4*)(op + 4) = v1;
        }
      }
      __syncthreads();
    } // stages
  } // steps
}

extern "C" void kernel_launch(void* const* d_in, const int* in_sizes, int n_in,
                              void* d_out, int out_size, void* d_ws, size_t ws_size,
                              hipStream_t stream) {
  (void)in_sizes; (void)n_in; (void)out_size; (void)ws_size;

  const float* ts = (const float*)d_in[0];
  const float* yi = (const float*)d_in[1];
  const float* w1 = (const float*)d_in[2];
  const float* b1 = (const float*)d_in[3];
  const float* w2 = (const float*)d_in[4];
  const float* b2 = (const float*)d_in[5];
  const float* w3 = (const float*)d_in[6];
  const float* b3 = (const float*)d_in[7];
  const float* Am = (const float*)d_in[8];
  float* outp = (float*)d_out;
  unsigned short* wsb = (unsigned short*)d_ws;

  (void)hipFuncSetAttribute(reinterpret_cast<const void*>(ode_kernel),
                            hipFuncAttributeMaxDynamicSharedMemorySize,
                            SMEM_BYTES);

  prep_kernel<<<512, 256, 0, stream>>>(w1, w2, w3, wsb);
  ode_kernel<<<dim3(NWG), dim3(NTHR), SMEM_BYTES, stream>>>(
      ts, yi, b1, b2, b3, Am, outp, wsb);
}